// Round 3
// baseline (1200.233 us; speedup 1.0000x reference)
//
#include <hip/hip_runtime.h>
#include <math.h>

#define BB 8
#define NN 50000
#define FF 256
#define KK 1024

// ---------- helpers ----------
__device__ __forceinline__ unsigned long long key64(double x) {
    unsigned long long u = (unsigned long long)__double_as_longlong(x);
    // monotone map: negative -> flip all bits, positive -> flip sign bit
    u ^= (u & 0x8000000000000000ull) ? 0xFFFFFFFFFFFFFFFFull : 0x8000000000000000ull;
    return u;
}
__device__ __forceinline__ double key_to_double(unsigned long long k) {
    unsigned long long u = (k & 0x8000000000000000ull) ? (k ^ 0x8000000000000000ull) : ~k;
    return __longlong_as_double((long long)u);
}

// ---------- zero the global histogram (ws is poisoned 0xAA) ----------
__global__ __launch_bounds__(1024) void zero_kernel(unsigned int* __restrict__ p, int n) {
    int i = blockIdx.x * 1024 + threadIdx.x;
    if (i < n) p[i] = 0u;
}

// ---------- phase 1: scores + direct global 11-bit histogram ----------
// Wave-per-row-group: 8 rows in flight per wave (ILP for loads + shuffle chains).
// grid = 512 blocks = exactly 2 blocks/CU; grid-stride over 50000 8-row groups.
__global__ __launch_bounds__(256) void score_kernel(const float* __restrict__ emb,
                                                    const float* __restrict__ mask,
                                                    const float* __restrict__ scorer,
                                                    double* __restrict__ scores,
                                                    unsigned int* __restrict__ ghist) {
    const int lane = threadIdx.x & 63;
    const int wave = threadIdx.x >> 6;
    const int gw   = blockIdx.x * 4 + wave;   // global wave id, 2048 waves
    const int nw   = 512 * 4;

    float4 sc = ((const float4*)scorer)[lane];
    double n2 = (double)sc.x * sc.x + (double)sc.y * sc.y +
                (double)sc.z * sc.z + (double)sc.w * sc.w;
    #pragma unroll
    for (int off = 32; off; off >>= 1) n2 += __shfl_xor(n2, off, 64);
    const double inv_norm = 1.0 / sqrt(n2);

    // 50000 groups of 8 rows (6250 per batch; 50000 % 8 == 0)
    for (int g = gw; g < 50000; g += nw) {
        const int b  = g / 6250;
        const int n0 = (g % 6250) * 8;
        const float* base = emb + ((long)b * NN + n0) * FF;

        double d[8];
        #pragma unroll
        for (int j = 0; j < 8; j++) {
            float4 v = ((const float4*)(base + j * FF))[lane];
            d[j] = (double)v.x * sc.x + (double)v.y * sc.y +
                   (double)v.z * sc.z + (double)v.w * sc.w;
        }
        #pragma unroll
        for (int off = 32; off; off >>= 1) {
            #pragma unroll
            for (int j = 0; j < 8; j++) d[j] += __shfl_xor(d[j], off, 64);
        }
        // epilogue across lanes 0..7: lane j takes row j
        double dsel = d[0];
        #pragma unroll
        for (int j = 1; j < 8; j++) dsel = (lane == j) ? d[j] : dsel;
        if (lane < 8) {
            double s = dsel * inv_norm + (double)mask[(long)b * NN + n0 + lane];
            unsigned long long k = key64(s);
            atomicAdd(&ghist[b * 2048 + (unsigned)(k >> 53)], 1u);
            scores[(long)b * NN + n0 + lane] = s;
        }
    }
}

// ---------- phase 2: per-batch exact top-K (desc value, ties -> asc index) ----------
// One 1024-thread block per batch. hist1 precomputed by score_kernel; one
// suffix scan -> bin1; ONE score pass collects superset {key>>53 >= bin1}
// (M ~ 1100 <= 4096); O(M^2) LDS-broadcast rank emits exact order.
__global__ __launch_bounds__(1024) void select_kernel(const double* __restrict__ scores,
                                                      const unsigned int* __restrict__ ghist,
                                                      int* __restrict__ topk_idx,
                                                      float* __restrict__ gate) {
    const int b   = blockIdx.x;
    const int tid = threadIdx.x;
    const double* sc = scores + (long)b * NN;

    __shared__ unsigned int h[2048];
    __shared__ unsigned long long keyA[4096];
    __shared__ int idxA[4096];
    __shared__ int bin1_s;
    __shared__ unsigned int cnt;

    const int i0 = tid, i1 = tid + 1024;
    h[i0] = ghist[b * 2048 + i0];
    h[i1] = ghist[b * 2048 + i1];
    if (tid == 0) cnt = 0u;
    __syncthreads();

    // suffix scan (Hillis-Steele, 11 steps)
    for (int off = 1; off < 2048; off <<= 1) {
        unsigned a0 = (i0 + off < 2048) ? h[i0 + off] : 0u;
        unsigned a1 = (i1 + off < 2048) ? h[i1 + off] : 0u;
        __syncthreads();
        h[i0] += a0; h[i1] += a1;
        __syncthreads();
    }
    if (h[i0] >= (unsigned)KK && (i0 == 2047 || h[i0 + 1] < (unsigned)KK)) bin1_s = i0;
    if (h[i1] >= (unsigned)KK && (i1 == 2047 || h[i1 + 1] < (unsigned)KK)) bin1_s = i1;
    __syncthreads();
    const unsigned long long bin1 = (unsigned long long)bin1_s;

    // single pass: collect everything in bins >= bin1
    for (int i = tid; i < NN / 2; i += 1024) {
        double2 v = ((const double2*)sc)[i];
        unsigned long long k0 = key64(v.x), k1 = key64(v.y);
        if ((k0 >> 53) >= bin1) {
            unsigned p = atomicAdd(&cnt, 1u);
            if (p < 4096u) { keyA[p] = k0; idxA[p] = 2 * i; }
        }
        if ((k1 >> 53) >= bin1) {
            unsigned p = atomicAdd(&cnt, 1u);
            if (p < 4096u) { keyA[p] = k1; idxA[p] = 2 * i + 1; }
        }
    }
    __syncthreads();
    const int M = (int)(cnt < 4096u ? cnt : 4096u);

    // O(M^2) rank: rank(i) = #{j: key_j > key_i or (key_j == key_i and idx_j < idx_i)}
    for (int i = tid; i < M; i += 1024) {
        const unsigned long long ki = keyA[i];
        const int ii = idxA[i];
        int rank = 0;
        for (int j = 0; j < M; ++j) {
            const unsigned long long kj = keyA[j];
            rank += (kj > ki) || (kj == ki && idxA[j] < ii);
        }
        if (rank < KK) {
            topk_idx[b * KK + rank] = ii;
            gate[b * KK + rank]     = tanhf((float)key_to_double(ki));
        }
    }
}

// ---------- phase 3: out[b,f,k] = emb[b, idx[b,k], f] * gate[b,k] ----------
__global__ __launch_bounds__(256) void gather_kernel(const float* __restrict__ emb,
                                                     const int* __restrict__ topk_idx,
                                                     const float* __restrict__ gate,
                                                     float* __restrict__ out) {
    const int b  = blockIdx.x >> 5;
    const int kt = blockIdx.x & 31;
    const int k0 = kt * 32;
    const int tid = threadIdx.x;

    __shared__ float tile[32][FF + 4];
    __shared__ int   s_idx[32];
    __shared__ float s_gate[32];

    if (tid < 32) {
        s_idx[tid]  = topk_idx[b * KK + k0 + tid];
        s_gate[tid] = gate[b * KK + k0 + tid];
    }
    __syncthreads();

    const int g = tid >> 6, lane = tid & 63;
    #pragma unroll
    for (int i = 0; i < 8; i++) {
        int kl = i * 4 + g;
        int row = s_idx[kl];
        float gt = s_gate[kl];
        float4 v = ((const float4*)(emb + ((long)b * NN + row) * FF))[lane];
        float* t = &tile[kl][lane * 4];
        t[0] = v.x * gt; t[1] = v.y * gt; t[2] = v.z * gt; t[3] = v.w * gt;
    }
    __syncthreads();

    const long outbase = ((long)b * FF) * KK + k0;
    #pragma unroll
    for (int c = 0; c < 32; c++) {
        int linear = c * 256 + tid;
        int f = linear >> 5;
        int k = linear & 31;
        out[outbase + (long)f * KK + k] = tile[k][f];
    }
}

extern "C" void kernel_launch(void* const* d_in, const int* in_sizes, int n_in,
                              void* d_out, int out_size, void* d_ws, size_t ws_size,
                              hipStream_t stream) {
    const float* emb    = (const float*)d_in[0];  // [B, N, F] fp32
    const float* mask   = (const float*)d_in[1];  // [B, N] fp32
    const float* scorer = (const float*)d_in[2];  // [F, 1] fp32
    float* out = (float*)d_out;                   // [B, F, K] fp32

    char* wsb = (char*)d_ws;
    double*       scores  = (double*)wsb;                               // B*N doubles = 3.2 MB
    unsigned int* ghist   = (unsigned int*)(wsb + sizeof(double) * BB * NN);
    int*          topkidx = (int*)((char*)ghist + sizeof(unsigned int) * BB * 2048);
    float*        gatep   = (float*)((char*)topkidx + sizeof(int) * BB * KK);

    zero_kernel<<<16, 1024, 0, stream>>>(ghist, BB * 2048);
    score_kernel<<<512, 256, 0, stream>>>(emb, mask, scorer, scores, ghist);
    select_kernel<<<BB, 1024, 0, stream>>>(scores, ghist, topkidx, gatep);
    gather_kernel<<<BB * 32, 256, 0, stream>>>(emb, topkidx, gatep, out);
}

// Round 4
// 726.662 us; speedup vs baseline: 1.6517x; 1.6517x over previous
//
#include <hip/hip_runtime.h>
#include <math.h>

#define BB 8
#define NN 50000
#define FF 256
#define KK 1024
#define GROUPS 50000        // 8-row groups over the flat [B*N] rows (NN % 8 == 0)
#define NWAVES 8192         // 2048 blocks * 4 waves = 32 waves/CU

// ---------- helpers ----------
__device__ __forceinline__ unsigned long long key64(double x) {
    unsigned long long u = (unsigned long long)__double_as_longlong(x);
    // monotone map: negative -> flip all bits, positive -> flip sign bit
    u ^= (u & 0x8000000000000000ull) ? 0xFFFFFFFFFFFFFFFFull : 0x8000000000000000ull;
    return u;
}
__device__ __forceinline__ double key_to_double(unsigned long long k) {
    unsigned long long u = (k & 0x8000000000000000ull) ? (k ^ 0x8000000000000000ull) : ~k;
    return __longlong_as_double((long long)u);
}

// ---------- phase 1: pure streaming scores (no atomics anywhere) ----------
// Wave-per-8-row-group, grid-stride over 50000 groups. Lane i loads float4 at
// f=4i (64 lanes x 16B = 1KB contiguous per row). Reduction: 3 butterfly
// levels inside 8-lane groups (24 dbl-shuffles), select d[lane&7], 3 levels
// across groups (3 dbl-shuffles) -> lanes 0..7 hold the 8 full dots.
__global__ __launch_bounds__(256) void score_kernel(const float* __restrict__ emb,
                                                    const float* __restrict__ mask,
                                                    const float* __restrict__ scorer,
                                                    double* __restrict__ scores) {
    const int lane = threadIdx.x & 63;
    const int wave = threadIdx.x >> 6;
    const int gw   = blockIdx.x * 4 + wave;

    float4 sc = ((const float4*)scorer)[lane];
    double n2 = (double)sc.x * sc.x + (double)sc.y * sc.y +
                (double)sc.z * sc.z + (double)sc.w * sc.w;
    #pragma unroll
    for (int off = 32; off; off >>= 1) n2 += __shfl_xor(n2, off, 64);
    const double inv_norm = 1.0 / sqrt(n2);

    for (int g = gw; g < GROUPS; g += NWAVES) {
        const float* base = emb + (long)g * 8 * FF;
        double d[8];
        #pragma unroll
        for (int j = 0; j < 8; j++) {
            float4 v = ((const float4*)(base + j * FF))[lane];
            d[j] = (double)v.x * sc.x + (double)v.y * sc.y +
                   (double)v.z * sc.z + (double)v.w * sc.w;
        }
        // butterfly within 8-lane groups
        #pragma unroll
        for (int off = 1; off <= 4; off <<= 1) {
            #pragma unroll
            for (int j = 0; j < 8; j++) d[j] += __shfl_xor(d[j], off, 64);
        }
        // lane L takes row (L&7)'s partial for group (L>>3)
        double v = d[0];
        #pragma unroll
        for (int j = 1; j < 8; j++) v = ((lane & 7) == j) ? d[j] : v;
        // butterfly across the 8 groups
        #pragma unroll
        for (int off = 8; off <= 32; off <<= 1) v += __shfl_xor(v, off, 64);

        if (lane < 8) {
            double s = v * inv_norm + (double)mask[g * 8 + lane];
            scores[g * 8 + lane] = s;   // 64B contiguous store from lanes 0..7
        }
    }
}

// ---------- phase 2: per-batch exact top-K (desc value, ties -> asc index) ----------
// One 1024-thread block per batch. Pass A: 11-bit histogram of key>>53 into 4
// LDS sub-hists (cuts hot-bin atomic serialization 4x). Suffix scan -> bin1
// (first bin with cum-from-top >= K). Pass B: collect superset {key>>53 >= bin1}
// (M ~ 1100 <= 4096). O(M^2) LDS-broadcast rank emits exact order.
__global__ __launch_bounds__(1024) void select_kernel(const double* __restrict__ scores,
                                                      int* __restrict__ topk_idx,
                                                      float* __restrict__ gate) {
    const int b   = blockIdx.x;
    const int tid = threadIdx.x;
    const double* sc = scores + (long)b * NN;

    __shared__ unsigned int h4[4][2048];
    __shared__ unsigned int h[2048];
    __shared__ unsigned long long keyA[4096];
    __shared__ int idxA[4096];
    __shared__ int bin1_s;
    __shared__ unsigned int cnt;

    const int i0 = tid, i1 = tid + 1024;
    const int sub = (tid >> 6) & 3;   // wave % 4

    #pragma unroll
    for (int s = 0; s < 4; s++) { h4[s][i0] = 0u; h4[s][i1] = 0u; }
    if (tid == 0) cnt = 0u;
    __syncthreads();

    // pass A: histogram
    for (int i = tid; i < NN / 2; i += 1024) {
        double2 v = ((const double2*)sc)[i];
        atomicAdd(&h4[sub][(unsigned)(key64(v.x) >> 53)], 1u);
        atomicAdd(&h4[sub][(unsigned)(key64(v.y) >> 53)], 1u);
    }
    __syncthreads();
    h[i0] = h4[0][i0] + h4[1][i0] + h4[2][i0] + h4[3][i0];
    h[i1] = h4[0][i1] + h4[1][i1] + h4[2][i1] + h4[3][i1];
    __syncthreads();

    // suffix scan (Hillis-Steele, 11 steps)
    for (int off = 1; off < 2048; off <<= 1) {
        unsigned a0 = (i0 + off < 2048) ? h[i0 + off] : 0u;
        unsigned a1 = (i1 + off < 2048) ? h[i1 + off] : 0u;
        __syncthreads();
        h[i0] += a0; h[i1] += a1;
        __syncthreads();
    }
    if (h[i0] >= (unsigned)KK && (i0 == 2047 || h[i0 + 1] < (unsigned)KK)) bin1_s = i0;
    if (h[i1] >= (unsigned)KK && (i1 == 2047 || h[i1 + 1] < (unsigned)KK)) bin1_s = i1;
    __syncthreads();
    const unsigned long long bin1 = (unsigned long long)bin1_s;

    // pass B: collect everything in bins >= bin1
    for (int i = tid; i < NN / 2; i += 1024) {
        double2 v = ((const double2*)sc)[i];
        unsigned long long k0 = key64(v.x), k1 = key64(v.y);
        if ((k0 >> 53) >= bin1) {
            unsigned p = atomicAdd(&cnt, 1u);
            if (p < 4096u) { keyA[p] = k0; idxA[p] = 2 * i; }
        }
        if ((k1 >> 53) >= bin1) {
            unsigned p = atomicAdd(&cnt, 1u);
            if (p < 4096u) { keyA[p] = k1; idxA[p] = 2 * i + 1; }
        }
    }
    __syncthreads();
    const int M = (int)(cnt < 4096u ? cnt : 4096u);

    // O(M^2) rank: rank(i) = #{j: key_j > key_i or (key_j == key_i and idx_j < idx_i)}
    for (int i = tid; i < M; i += 1024) {
        const unsigned long long ki = keyA[i];
        const int ii = idxA[i];
        int rank = 0;
        for (int j = 0; j < M; ++j) {
            const unsigned long long kj = keyA[j];
            rank += (kj > ki) || (kj == ki && idxA[j] < ii);
        }
        if (rank < KK) {
            topk_idx[b * KK + rank] = ii;
            gate[b * KK + rank]     = tanhf((float)key_to_double(ki));
        }
    }
}

// ---------- phase 3: out[b,f,k] = emb[b, idx[b,k], f] * gate[b,k] ----------
__global__ __launch_bounds__(256) void gather_kernel(const float* __restrict__ emb,
                                                     const int* __restrict__ topk_idx,
                                                     const float* __restrict__ gate,
                                                     float* __restrict__ out) {
    const int b  = blockIdx.x >> 5;
    const int kt = blockIdx.x & 31;
    const int k0 = kt * 32;
    const int tid = threadIdx.x;

    __shared__ float tile[32][FF + 4];
    __shared__ int   s_idx[32];
    __shared__ float s_gate[32];

    if (tid < 32) {
        s_idx[tid]  = topk_idx[b * KK + k0 + tid];
        s_gate[tid] = gate[b * KK + k0 + tid];
    }
    __syncthreads();

    const int g = tid >> 6, lane = tid & 63;
    #pragma unroll
    for (int i = 0; i < 8; i++) {
        int kl = i * 4 + g;
        int row = s_idx[kl];
        float gt = s_gate[kl];
        float4 v = ((const float4*)(emb + ((long)b * NN + row) * FF))[lane];
        float* t = &tile[kl][lane * 4];
        t[0] = v.x * gt; t[1] = v.y * gt; t[2] = v.z * gt; t[3] = v.w * gt;
    }
    __syncthreads();

    const long outbase = ((long)b * FF) * KK + k0;
    #pragma unroll
    for (int c = 0; c < 32; c++) {
        int linear = c * 256 + tid;
        int f = linear >> 5;
        int k = linear & 31;
        out[outbase + (long)f * KK + k] = tile[k][f];
    }
}

extern "C" void kernel_launch(void* const* d_in, const int* in_sizes, int n_in,
                              void* d_out, int out_size, void* d_ws, size_t ws_size,
                              hipStream_t stream) {
    const float* emb    = (const float*)d_in[0];  // [B, N, F] fp32
    const float* mask   = (const float*)d_in[1];  // [B, N] fp32
    const float* scorer = (const float*)d_in[2];  // [F, 1] fp32
    float* out = (float*)d_out;                   // [B, F, K] fp32

    char* wsb = (char*)d_ws;
    double* scores  = (double*)wsb;                                   // B*N doubles = 3.2 MB
    int*    topkidx = (int*)(wsb + sizeof(double) * BB * NN);
    float*  gatep   = (float*)((char*)topkidx + sizeof(int) * BB * KK);

    score_kernel<<<2048, 256, 0, stream>>>(emb, mask, scorer, scores);
    select_kernel<<<BB, 1024, 0, stream>>>(scores, topkidx, gatep);
    gather_kernel<<<BB * 32, 256, 0, stream>>>(emb, topkidx, gatep, out);
}